// Round 3
// baseline (606.761 us; speedup 1.0000x reference)
//
#include <hip/hip_runtime.h>

typedef unsigned short u16;
typedef unsigned int   u32;
typedef unsigned long long u64;

#define HID 128
#define KPB 256      // keys per coarse bucket (shift 8)
#define NBMAX 512    // max coarse buckets (actual: 391)
#define IPB 2048     // incidences per partition workgroup
#define CAP 6144     // LDS val-staging capacity per bucket (mean ~3070)

typedef __bf16 bf16x8 __attribute__((ext_vector_type(8)));
typedef float  f32x4  __attribute__((ext_vector_type(4)));
typedef u32    u32x4  __attribute__((ext_vector_type(4)));
typedef int    i32x4  __attribute__((ext_vector_type(4)));

__device__ inline float u2f(u32 u){ union{u32 u;float f;} v; v.u=u; return v.f; }
__device__ inline u32   f2u(float f){ union{float f;u32 u;} v; v.f=f; return v.u; }
__device__ inline u32  f2bfu(float f){ u32 b=f2u(f); return ((b + 0x7FFFu + ((b>>16)&1u))>>16)&0xFFFFu; }
__device__ inline float blo(u32 u){ return u2f(u<<16); }
__device__ inline float bhi(u32 u){ return u2f(u & 0xFFFF0000u); }
__device__ inline u32  pk(float lo, float hi){ return (f2bfu(hi)<<16) | f2bfu(lo); }

// Sliced-table layout: tab[4][M][32] u16 — slice s is a contiguous 3.2 MB block,
// slice-rows are 64 B and line-aligned; XCD k (= blockIdx%8) only touches slice k&3,
// which fits its private 4 MB L2. Everything EXCEPT the table is loaded/stored
// non-temporally so the table slice stays L2-resident.

// ---------- K1: coarse histogram (blocks [0,nhb)) ∪ W-fragment conversion (rest) ----------
__global__ __launch_bounds__(256) void k_hist_wfrag(const int* __restrict__ nidx, const int* __restrict__ eidx,
                                                    int* __restrict__ hist, int nE, int nN, int nb, int nhb,
                                                    const float* __restrict__ W1, const float* __restrict__ W2,
                                                    u16* __restrict__ W1f, u16* __restrict__ W2f){
    __shared__ int h[NBMAX];
    if ((int)blockIdx.x < nhb){
        for (int t=threadIdx.x; t<nb; t+=256) h[t]=0;
        __syncthreads();
        int base = blockIdx.x*IPB;
        for (int k=threadIdx.x; k<IPB; k+=256){
            int j = base+k;
            if (j < nE){
                atomicAdd(&h[nidx[j]>>8], 1);
                atomicAdd(&h[(nN+eidx[j])>>8], 1);
            }
        }
        __syncthreads();
        for (int t=threadIdx.x; t<nb; t+=256) if (h[t]) atomicAdd(&hist[t], h[t]);
    } else {
        int gid = ((int)blockIdx.x - nhb)*256 + threadIdx.x;   // 32768 total
        const float* W = (gid < 16384) ? W1 : W2;
        u16* Wf = (gid < 16384) ? W1f : W2f;
        int id = gid & 16383;
        int i = id & 7, l = (id>>3)&63, j = (id>>9)&7, s = id>>12;
        Wf[id] = (u16)f2bfu(W[(s*32 + ((l>>4)<<3) + i)*HID + (j<<4) + (l&15)]);
    }
}

// ---------- K2: partition into buckets (blocks [0,npb)) ∪ layer-1 GEMM fp32-A (rest) ----------
// GEMM epilogue writes SLICE-MAJOR: C[(slice*M + row)*32 + col_in_slice]
__global__ __launch_bounds__(256) void k_part_gemm(const int* __restrict__ nidx, const int* __restrict__ eidx,
                                                   const int* __restrict__ hist, int* __restrict__ bfill,
                                                   u64* __restrict__ pairs, int nE, int nN, int nb, int npb,
                                                   const float* __restrict__ A, const u16* __restrict__ Wf,
                                                   u16* __restrict__ C, int M){
    __shared__ int h[NBMAX], rsv[NBMAX], fl[NBMAX], bb[NBMAX], sd[256];
    int t = threadIdx.x;
    if ((int)blockIdx.x < npb){
        for (int i=t; i<nb; i+=256){ h[i]=0; fl[i]=0; }
        __syncthreads();
        int base = blockIdx.x*IPB;
        for (int k=t; k<IPB; k+=256){
            int j = base+k;
            if (j < nE){
                atomicAdd(&h[nidx[j]>>8], 1);
                atomicAdd(&h[(nN+eidx[j])>>8], 1);
            }
        }
        int c0 = (2*t   < nb) ? hist[2*t]   : 0;
        int c1 = (2*t+1 < nb) ? hist[2*t+1] : 0;
        int s = c0 + c1;
        sd[t] = s; __syncthreads();
        for (int o=1;o<256;o<<=1){ int u = (t>=o)? sd[t-o] : 0; __syncthreads(); sd[t]+=u; __syncthreads(); }
        int ex = sd[t] - s;
        if (2*t   < nb) bb[2*t]   = ex;
        if (2*t+1 < nb) bb[2*t+1] = ex + c0;
        __syncthreads();
        for (int i=t; i<nb; i+=256){ if (h[i]) rsv[i] = bb[i] + atomicAdd(&bfill[i], h[i]); }
        __syncthreads();
        for (int k=t; k<IPB; k+=256){
            int j = base+k;
            if (j < nE){
                int n = nidx[j], e = eidx[j];
                int b1 = n>>8;
                int p1 = rsv[b1] + atomicAdd(&fl[b1], 1);
                pairs[p1] = ((u64)(u32)n << 32) | (u32)e;
                int k2 = nN + e;
                int b2 = k2>>8;
                int p2 = rsv[b2] + atomicAdd(&fl[b2], 1);
                pairs[p2] = ((u64)(u32)k2 << 32) | (u32)n;
            }
        }
    } else {
        int wave = ((int)blockIdx.x - npb)*4 + (t>>6);
        int lane = t & 63;
        int rtiles = M >> 4;
        if (wave >= rtiles) return;
        int row0 = wave << 4;
        const float* Arow = A + (size_t)(row0 + (lane&15))*HID + ((lane>>4)<<3);
        const bf16x8* Wp = reinterpret_cast<const bf16x8*>(Wf) + lane;
        f32x4 acc[8];
        #pragma unroll
        for (int j=0;j<8;++j) acc[j] = (f32x4){0.f,0.f,0.f,0.f};
        #pragma unroll
        for (int s=0;s<4;++s){
            float4 f0 = *reinterpret_cast<const float4*>(Arow + s*32);
            float4 f1 = *reinterpret_cast<const float4*>(Arow + s*32 + 4);
            union { u16 h[8]; bf16x8 v; } au;
            au.h[0]=(u16)f2bfu(f0.x); au.h[1]=(u16)f2bfu(f0.y); au.h[2]=(u16)f2bfu(f0.z); au.h[3]=(u16)f2bfu(f0.w);
            au.h[4]=(u16)f2bfu(f1.x); au.h[5]=(u16)f2bfu(f1.y); au.h[6]=(u16)f2bfu(f1.z); au.h[7]=(u16)f2bfu(f1.w);
            #pragma unroll
            for (int j=0;j<8;++j){
                bf16x8 b = Wp[(s*8 + j)*64];
                acc[j] = __builtin_amdgcn_mfma_f32_16x16x32_bf16(au.v, b, acc[j], 0, 0, 0);
            }
        }
        int r0 = row0 + ((lane>>4)<<2);
        int c0 = lane & 15;
        #pragma unroll
        for (int j=0;j<8;++j){
            size_t sb = ((size_t)(j>>1)*M)*32 + ((j&1)<<4) + c0;
            #pragma unroll
            for (int r=0;r<4;++r){
                __builtin_nontemporal_store((u16)f2bfu(acc[j][r]), &C[sb + (size_t)(r0+r)*32]);
            }
        }
    }
}

// ---------- per-bucket fine counting sort in LDS (computes own base locally) ----------
__global__ __launch_bounds__(256) void k_bucket(const u64* __restrict__ pairs, const int* __restrict__ hist,
                                                int* __restrict__ csr, int* __restrict__ off,
                                                int nkeys, int nb, int total){
    __shared__ int cntS[KPB];
    __shared__ int fillS[KPB];
    __shared__ int bbS[NBMAX+1];
    __shared__ int sd[256];
    __shared__ int vals[CAP];
    int b = blockIdx.x;
    int t = threadIdx.x;
    if (b == 0 && t == 0) off[nkeys] = total;
    int c0 = (2*t   < nb) ? hist[2*t]   : 0;
    int c1 = (2*t+1 < nb) ? hist[2*t+1] : 0;
    int s = c0 + c1;
    sd[t] = s; __syncthreads();
    for (int o=1;o<256;o<<=1){ int u = (t>=o)? sd[t-o] : 0; __syncthreads(); sd[t]+=u; __syncthreads(); }
    int ex = sd[t] - s;
    if (2*t   <= nb) bbS[2*t]   = ex;
    if (2*t+1 <= nb) bbS[2*t+1] = ex + c0;
    __syncthreads();
    int base = bbS[b];
    int n = bbS[b+1] - base;
    int k0 = b * KPB;

    cntS[t] = 0;
    __syncthreads();
    for (int i=t; i<n; i+=256){
        u64 p = pairs[base+i];
        atomicAdd(&cntS[(int)(p>>32) - k0], 1);
    }
    __syncthreads();
    int c = cntS[t];
    __syncthreads();
    fillS[t] = c; __syncthreads();
    for (int o=1;o<256;o<<=1){ int u = (t>=o)? fillS[t-o] : 0; __syncthreads(); fillS[t]+=u; __syncthreads(); }
    int ex2 = fillS[t] - c;
    __syncthreads();
    fillS[t] = ex2;
    __syncthreads();
    int k = k0 + t;
    if (k < nkeys) off[k] = base + ex2;
    bool fits = (n <= CAP);
    for (int i=t; i<n; i+=256){
        u64 p = pairs[base+i];
        int kl = (int)(p>>32) - k0;
        int pos = atomicAdd(&fillS[kl], 1);
        if (fits) vals[pos] = (int)(u32)p;
        else      csr[base+pos] = (int)(u32)p;
    }
    __syncthreads();
    if (fits){
        for (int i=t; i<n; i+=256) csr[base+i] = vals[i];
    }
}

// ---------- XCD-sliced CSR-gather segment mean (slice-major table) ----------
// 4 lanes per dest row; each iteration processes 8 incidences.
// Incidence indices are loaded directly as two aligned i32x4 (same addr within the
// 4-lane group => broadcast) — no shuffles on the critical path. Head/tail entries
// of the 8-aligned window are masked per-entry (masked lanes never form the gather
// address; the idx over-read lands in the csr/pairs workspace, always mapped).
// csr loads and all outputs are non-temporal so the table slice owns the L2.
// MODE 0: out bf16 slice-major | MODE 1: out bf16 row-major, + bias + prelu
// MODE 2: out fp32 row-major, + bias + resid + prelu
template<int MODE>
__global__ __launch_bounds__(256) void k_aggs(const u32* __restrict__ tab, const int* __restrict__ csr,
                                              const int* __restrict__ off, void* __restrict__ outp,
                                              const float* __restrict__ bias, const float* __restrict__ resid,
                                              const float* __restrict__ aptr, int nrows){
    int slice = blockIdx.x & 3;
    int dt    = blockIdx.x >> 2;
    int t = threadIdx.x;
    int lane = t & 63;
    int grp = lane >> 2, c4 = lane & 3;
    int d = dt*64 + ((t>>6)<<4) + grp;
    if (d >= nrows) return;
    int start = off[d], end = off[d+1];
    int deg = end - start;
    const u32* tslice = tab + (size_t)slice*nrows*16 + (c4<<2);   // slice-row stride: 16 u32

    float a0=0.f,a1=0.f,a2=0.f,a3=0.f,a4=0.f,a5=0.f,a6=0.f,a7=0.f;
    for (int pos = start & ~7; pos < end; pos += 8){
        i32x4 ia = __builtin_nontemporal_load(reinterpret_cast<const i32x4*>(csr + pos));
        i32x4 ib = __builtin_nontemporal_load(reinterpret_cast<const i32x4*>(csr + pos + 4));
        int sidx[8];
        sidx[0]=ia.x; sidx[1]=ia.y; sidx[2]=ia.z; sidx[3]=ia.w;
        sidx[4]=ib.x; sidx[5]=ib.y; sidx[6]=ib.z; sidx[7]=ib.w;
        u32x4 v[8];
        #pragma unroll
        for (int k=0;k<8;++k) v[k] = (u32x4){0u,0u,0u,0u};
        #pragma unroll
        for (int k=0;k<8;++k){
            if (pos+k >= start && pos+k < end)
                v[k] = *reinterpret_cast<const u32x4*>(tslice + (size_t)sidx[k]*16);
        }
        #pragma unroll
        for (int k=0;k<8;++k){
            a0 += blo(v[k].x); a1 += bhi(v[k].x);
            a2 += blo(v[k].y); a3 += bhi(v[k].y);
            a4 += blo(v[k].z); a5 += bhi(v[k].z);
            a6 += blo(v[k].w); a7 += bhi(v[k].w);
        }
    }
    float s = (deg > 0) ? 1.0f/(float)deg : 0.f;
    a0*=s; a1*=s; a2*=s; a3*=s; a4*=s; a5*=s; a6*=s; a7*=s;
    if constexpr (MODE >= 1){
        const f32x4* bp = reinterpret_cast<const f32x4*>(bias + slice*32 + (c4<<3));
        f32x4 b0 = bp[0], b1v = bp[1];
        a0+=b0.x; a1+=b0.y; a2+=b0.z; a3+=b0.w;
        a4+=b1v.x; a5+=b1v.y; a6+=b1v.z; a7+=b1v.w;
        if constexpr (MODE == 2){
            const f32x4* rp = reinterpret_cast<const f32x4*>(resid + (size_t)d*HID + slice*32 + (c4<<3));
            f32x4 r0 = __builtin_nontemporal_load(rp);
            f32x4 r1 = __builtin_nontemporal_load(rp + 1);
            a0+=r0.x; a1+=r0.y; a2+=r0.z; a3+=r0.w;
            a4+=r1.x; a5+=r1.y; a6+=r1.z; a7+=r1.w;
        }
        float al = aptr[0];
        a0 = (a0>=0.f)? a0 : al*a0;  a1 = (a1>=0.f)? a1 : al*a1;
        a2 = (a2>=0.f)? a2 : al*a2;  a3 = (a3>=0.f)? a3 : al*a3;
        a4 = (a4>=0.f)? a4 : al*a4;  a5 = (a5>=0.f)? a5 : al*a5;
        a6 = (a6>=0.f)? a6 : al*a6;  a7 = (a7>=0.f)? a7 : al*a7;
    }
    if constexpr (MODE == 2){
        f32x4* op = reinterpret_cast<f32x4*>((float*)outp + (size_t)d*HID + slice*32 + (c4<<3));
        __builtin_nontemporal_store((f32x4){a0,a1,a2,a3}, op);
        __builtin_nontemporal_store((f32x4){a4,a5,a6,a7}, op + 1);
    } else if constexpr (MODE == 1){
        // row-major bf16 (feeds the dense GEMM)
        u32x4 wv4 = (u32x4){ pk(a0,a1), pk(a2,a3), pk(a4,a5), pk(a6,a7) };
        __builtin_nontemporal_store(wv4,
            reinterpret_cast<u32x4*>((u32*)outp + (size_t)d*64 + slice*16 + (c4<<2)));
    } else {
        // slice-major bf16 (feeds the next sliced gather)
        u32x4 wv4 = (u32x4){ pk(a0,a1), pk(a2,a3), pk(a4,a5), pk(a6,a7) };
        __builtin_nontemporal_store(wv4,
            reinterpret_cast<u32x4*>((u32*)outp + ((size_t)slice*nrows + d)*16 + (c4<<2)));
    }
}

// ---------- standalone bf16 GEMM: C = A(bf16 row-major) @ Wf, slice-major output ----------
__global__ __launch_bounds__(256) void k_gemm_bf(const u16* __restrict__ A, const u16* __restrict__ Wf,
                                                 u16* __restrict__ C, int M){
    int wave = blockIdx.x*4 + ((int)threadIdx.x>>6);
    int lane = threadIdx.x & 63;
    int rtiles = M >> 4;
    if (wave >= rtiles) return;
    int row0 = wave << 4;
    const u16* Arow = A + (size_t)(row0 + (lane&15))*HID + ((lane>>4)<<3);
    const bf16x8* Wp = reinterpret_cast<const bf16x8*>(Wf) + lane;
    f32x4 acc[8];
    #pragma unroll
    for (int j=0;j<8;++j) acc[j] = (f32x4){0.f,0.f,0.f,0.f};
    #pragma unroll
    for (int s=0;s<4;++s){
        bf16x8 a = __builtin_nontemporal_load(reinterpret_cast<const bf16x8*>(Arow + s*32));
        #pragma unroll
        for (int j=0;j<8;++j){
            bf16x8 b = Wp[(s*8 + j)*64];
            acc[j] = __builtin_amdgcn_mfma_f32_16x16x32_bf16(a, b, acc[j], 0, 0, 0);
        }
    }
    int r0 = row0 + ((lane>>4)<<2);
    int c0 = lane & 15;
    #pragma unroll
    for (int j=0;j<8;++j){
        size_t sb = ((size_t)(j>>1)*M)*32 + ((j&1)<<4) + c0;
        #pragma unroll
        for (int r=0;r<4;++r){
            __builtin_nontemporal_store((u16)f2bfu(acc[j][r]), &C[sb + (size_t)(r0+r)*32]);
        }
    }
}

extern "C" void kernel_launch(void* const* d_in, const int* in_sizes, int n_in,
                              void* d_out, int out_size, void* d_ws, size_t ws_size,
                              hipStream_t stream){
    (void)n_in; (void)out_size; (void)ws_size;
    const float* x  = (const float*)d_in[0];
    const int*  hei = (const int*)  d_in[1];
    const float* W1 = (const float*)d_in[2];
    const float* b1 = (const float*)d_in[3];
    const float* W2 = (const float*)d_in[4];
    const float* b2 = (const float*)d_in[5];
    const float* ap = (const float*)d_in[6];

    const int nN = in_sizes[0] / HID;   // 50000
    const int nE = in_sizes[1] / 2;     // 600000
    const int* nidx = hei;
    const int* eidx = hei + nE;
    const int nkeys = 2*nN;
    const int nb    = (nkeys + KPB - 1) / KPB;   // 391

    char* w = (char*)d_ws;
    size_t o = 0;
    auto alloc = [&](size_t bytes)->void*{
        void* p = (void*)(w + o);
        o += (bytes + 255) & ~(size_t)255;
        return p;
    };
    int* hist  = (int*)alloc((size_t)NBMAX*sizeof(int));
    int* bfill = (int*)alloc((size_t)NBMAX*sizeof(int));
    int* off   = (int*)alloc(((size_t)nkeys+1)*sizeof(int));
    int* csr   = (int*)alloc((size_t)2*nE*sizeof(int));
    u64* pairs = (u64*)alloc((size_t)2*nE*sizeof(u64));
    u16* bufB  = (u16*)alloc((size_t)nN*HID*sizeof(u16));   // xw / hw (slice-major)
    u16* bufC  = (u16*)alloc((size_t)nN*HID*sizeof(u16));   // m / m2  (slice-major)
    u16* bufH  = (u16*)alloc((size_t)nN*HID*sizeof(u16));   // h (row-major, GEMM input)
    u16* w1f   = (u16*)alloc((size_t)HID*HID*sizeof(u16));
    u16* w2f   = (u16*)alloc((size_t)HID*HID*sizeof(u16));

    hipMemsetAsync(hist, 0, (size_t)2*NBMAX*sizeof(int), stream);   // hist + bfill (contiguous)

    const int pgrid  = (nE + IPB - 1)/IPB;       // 293
    const int rtiles = nN/16;                    // 3125
    const int ggrid  = (rtiles + 3)/4;           // 782
    const int dblk   = (nN + 63)/64;             // 782 dest tiles
    const int agrid  = 4*dblk;                   // × 4 column slices

    // K1: hist ∪ wfrag
    k_hist_wfrag<<<pgrid + 128, 256, 0, stream>>>(nidx, eidx, hist, nE, nN, nb, pgrid, W1, W2, w1f, w2f);
    // K2: part ∪ layer-1 gemm (fp32 A): xw = x @ W1 -> bufB (slice-major)
    k_part_gemm<<<pgrid + ggrid, 256, 0, stream>>>(nidx, eidx, hist, bfill, pairs, nE, nN, nb, pgrid,
                                                   x, w1f, bufB, nN);
    // K3: bucket (also writes off sentinel)
    k_bucket<<<nb, 256, 0, stream>>>(pairs, hist, csr, off, nkeys, nb, 2*nE);

    // layer 1: m = B^-1 H^T xw    (hyperedge side) -> bufC (slice-major)
    k_aggs<0><<<agrid, 256, 0, stream>>>((const u32*)bufB, csr, off + nN, bufC, nullptr, nullptr, nullptr, nN);
    // h = prelu(D^-1 H m + b1)    (node side) -> bufH (row-major)
    k_aggs<1><<<agrid, 256, 0, stream>>>((const u32*)bufC, csr, off, bufH, b1, nullptr, ap, nN);
    // hw = h @ W2 -> bufB (slice-major)
    k_gemm_bf<<<ggrid, 256, 0, stream>>>(bufH, w2f, bufB, nN);
    // layer 2: m2 = B^-1 H^T hw -> bufC (slice-major)
    k_aggs<0><<<agrid, 256, 0, stream>>>((const u32*)bufB, csr, off + nN, bufC, nullptr, nullptr, nullptr, nN);
    // out = prelu(D^-1 H m2 + b2 + x)
    k_aggs<2><<<agrid, 256, 0, stream>>>((const u32*)bufC, csr, off, d_out, b2, x, ap, nN);
}

// Round 4
// 230.341 us; speedup vs baseline: 2.6342x; 2.6342x over previous
//
#include <hip/hip_runtime.h>

typedef unsigned short u16;
typedef unsigned int   u32;
typedef unsigned long long u64;

#define HID 128
#define KPB 256      // keys per coarse bucket (shift 8)
#define NBMAX 512    // max coarse buckets (actual: 391)
#define IPB 2048     // incidences per partition workgroup
#define CAP 6144     // LDS val-staging capacity per bucket (mean ~3070)

typedef __bf16 bf16x8 __attribute__((ext_vector_type(8)));
typedef float  f32x4  __attribute__((ext_vector_type(4)));
typedef u32    u32x4  __attribute__((ext_vector_type(4)));

__device__ inline float u2f(u32 u){ union{u32 u;float f;} v; v.u=u; return v.f; }
__device__ inline u32   f2u(float f){ union{float f;u32 u;} v; v.f=f; return v.u; }
__device__ inline u32  f2bfu(float f){ u32 b=f2u(f); return ((b + 0x7FFFu + ((b>>16)&1u))>>16)&0xFFFFu; }
__device__ inline float blo(u32 u){ return u2f(u<<16); }
__device__ inline float bhi(u32 u){ return u2f(u & 0xFFFF0000u); }
__device__ inline u32  pk(float lo, float hi){ return (f2bfu(hi)<<16) | f2bfu(lo); }

// Sliced-table layout: tab[4][M][32] u16 — slice s is a contiguous 3.2 MB block,
// slice-rows are 64 B and line-aligned; XCD k (= blockIdx%8) only touches slice k&3,
// which fits its private 4 MB L2. Gather table + csr are CACHED (csr is only
// ~1.2 MB/XCD/pass); outputs are non-temporal so they don't evict the table.

// ---------- K1: coarse histogram (blocks [0,nhb)) ∪ W-fragment conversion (rest) ----------
__global__ __launch_bounds__(256) void k_hist_wfrag(const int* __restrict__ nidx, const int* __restrict__ eidx,
                                                    int* __restrict__ hist, int nE, int nN, int nb, int nhb,
                                                    const float* __restrict__ W1, const float* __restrict__ W2,
                                                    u16* __restrict__ W1f, u16* __restrict__ W2f){
    __shared__ int h[NBMAX];
    if ((int)blockIdx.x < nhb){
        for (int t=threadIdx.x; t<nb; t+=256) h[t]=0;
        __syncthreads();
        int base = blockIdx.x*IPB;
        for (int k=threadIdx.x; k<IPB; k+=256){
            int j = base+k;
            if (j < nE){
                atomicAdd(&h[nidx[j]>>8], 1);
                atomicAdd(&h[(nN+eidx[j])>>8], 1);
            }
        }
        __syncthreads();
        for (int t=threadIdx.x; t<nb; t+=256) if (h[t]) atomicAdd(&hist[t], h[t]);
    } else {
        int gid = ((int)blockIdx.x - nhb)*256 + threadIdx.x;   // 32768 total
        const float* W = (gid < 16384) ? W1 : W2;
        u16* Wf = (gid < 16384) ? W1f : W2f;
        int id = gid & 16383;
        int i = id & 7, l = (id>>3)&63, j = (id>>9)&7, s = id>>12;
        Wf[id] = (u16)f2bfu(W[(s*32 + ((l>>4)<<3) + i)*HID + (j<<4) + (l&15)]);
    }
}

// ---------- K2: partition into buckets (blocks [0,npb)) ∪ layer-1 GEMM fp32-A (rest) ----------
// GEMM epilogue writes SLICE-MAJOR: C[(slice*M + row)*32 + col_in_slice]
__global__ __launch_bounds__(256) void k_part_gemm(const int* __restrict__ nidx, const int* __restrict__ eidx,
                                                   const int* __restrict__ hist, int* __restrict__ bfill,
                                                   u64* __restrict__ pairs, int nE, int nN, int nb, int npb,
                                                   const float* __restrict__ A, const u16* __restrict__ Wf,
                                                   u16* __restrict__ C, int M){
    __shared__ int h[NBMAX], rsv[NBMAX], fl[NBMAX], bb[NBMAX], sd[256];
    int t = threadIdx.x;
    if ((int)blockIdx.x < npb){
        for (int i=t; i<nb; i+=256){ h[i]=0; fl[i]=0; }
        __syncthreads();
        int base = blockIdx.x*IPB;
        for (int k=t; k<IPB; k+=256){
            int j = base+k;
            if (j < nE){
                atomicAdd(&h[nidx[j]>>8], 1);
                atomicAdd(&h[(nN+eidx[j])>>8], 1);
            }
        }
        int c0 = (2*t   < nb) ? hist[2*t]   : 0;
        int c1 = (2*t+1 < nb) ? hist[2*t+1] : 0;
        int s = c0 + c1;
        sd[t] = s; __syncthreads();
        for (int o=1;o<256;o<<=1){ int u = (t>=o)? sd[t-o] : 0; __syncthreads(); sd[t]+=u; __syncthreads(); }
        int ex = sd[t] - s;
        if (2*t   < nb) bb[2*t]   = ex;
        if (2*t+1 < nb) bb[2*t+1] = ex + c0;
        __syncthreads();
        for (int i=t; i<nb; i+=256){ if (h[i]) rsv[i] = bb[i] + atomicAdd(&bfill[i], h[i]); }
        __syncthreads();
        for (int k=t; k<IPB; k+=256){
            int j = base+k;
            if (j < nE){
                int n = nidx[j], e = eidx[j];
                int b1 = n>>8;
                int p1 = rsv[b1] + atomicAdd(&fl[b1], 1);
                pairs[p1] = ((u64)(u32)n << 32) | (u32)e;
                int k2 = nN + e;
                int b2 = k2>>8;
                int p2 = rsv[b2] + atomicAdd(&fl[b2], 1);
                pairs[p2] = ((u64)(u32)k2 << 32) | (u32)n;
            }
        }
    } else {
        int wave = ((int)blockIdx.x - npb)*4 + (t>>6);
        int lane = t & 63;
        int rtiles = M >> 4;
        if (wave >= rtiles) return;
        int row0 = wave << 4;
        const float* Arow = A + (size_t)(row0 + (lane&15))*HID + ((lane>>4)<<3);
        const bf16x8* Wp = reinterpret_cast<const bf16x8*>(Wf) + lane;
        f32x4 acc[8];
        #pragma unroll
        for (int j=0;j<8;++j) acc[j] = (f32x4){0.f,0.f,0.f,0.f};
        #pragma unroll
        for (int s=0;s<4;++s){
            float4 f0 = *reinterpret_cast<const float4*>(Arow + s*32);
            float4 f1 = *reinterpret_cast<const float4*>(Arow + s*32 + 4);
            union { u16 h[8]; bf16x8 v; } au;
            au.h[0]=(u16)f2bfu(f0.x); au.h[1]=(u16)f2bfu(f0.y); au.h[2]=(u16)f2bfu(f0.z); au.h[3]=(u16)f2bfu(f0.w);
            au.h[4]=(u16)f2bfu(f1.x); au.h[5]=(u16)f2bfu(f1.y); au.h[6]=(u16)f2bfu(f1.z); au.h[7]=(u16)f2bfu(f1.w);
            #pragma unroll
            for (int j=0;j<8;++j){
                bf16x8 b = Wp[(s*8 + j)*64];
                acc[j] = __builtin_amdgcn_mfma_f32_16x16x32_bf16(au.v, b, acc[j], 0, 0, 0);
            }
        }
        int r0 = row0 + ((lane>>4)<<2);
        int c0 = lane & 15;
        #pragma unroll
        for (int j=0;j<8;++j){
            size_t sb = ((size_t)(j>>1)*M)*32 + ((j&1)<<4) + c0;
            #pragma unroll
            for (int r=0;r<4;++r){
                __builtin_nontemporal_store((u16)f2bfu(acc[j][r]), &C[sb + (size_t)(r0+r)*32]);
            }
        }
    }
}

// ---------- per-bucket fine counting sort in LDS (computes own base locally) ----------
__global__ __launch_bounds__(256) void k_bucket(const u64* __restrict__ pairs, const int* __restrict__ hist,
                                                int* __restrict__ csr, int* __restrict__ off,
                                                int nkeys, int nb, int total){
    __shared__ int cntS[KPB];
    __shared__ int fillS[KPB];
    __shared__ int bbS[NBMAX+1];
    __shared__ int sd[256];
    __shared__ int vals[CAP];
    int b = blockIdx.x;
    int t = threadIdx.x;
    if (b == 0 && t == 0) off[nkeys] = total;
    int c0 = (2*t   < nb) ? hist[2*t]   : 0;
    int c1 = (2*t+1 < nb) ? hist[2*t+1] : 0;
    int s = c0 + c1;
    sd[t] = s; __syncthreads();
    for (int o=1;o<256;o<<=1){ int u = (t>=o)? sd[t-o] : 0; __syncthreads(); sd[t]+=u; __syncthreads(); }
    int ex = sd[t] - s;
    if (2*t   <= nb) bbS[2*t]   = ex;
    if (2*t+1 <= nb) bbS[2*t+1] = ex + c0;
    __syncthreads();
    int base = bbS[b];
    int n = bbS[b+1] - base;
    int k0 = b * KPB;

    cntS[t] = 0;
    __syncthreads();
    for (int i=t; i<n; i+=256){
        u64 p = pairs[base+i];
        atomicAdd(&cntS[(int)(p>>32) - k0], 1);
    }
    __syncthreads();
    int c = cntS[t];
    __syncthreads();
    fillS[t] = c; __syncthreads();
    for (int o=1;o<256;o<<=1){ int u = (t>=o)? fillS[t-o] : 0; __syncthreads(); fillS[t]+=u; __syncthreads(); }
    int ex2 = fillS[t] - c;
    __syncthreads();
    fillS[t] = ex2;
    __syncthreads();
    int k = k0 + t;
    if (k < nkeys) off[k] = base + ex2;
    bool fits = (n <= CAP);
    for (int i=t; i<n; i+=256){
        u64 p = pairs[base+i];
        int kl = (int)(p>>32) - k0;
        int pos = atomicAdd(&fillS[kl], 1);
        if (fits) vals[pos] = (int)(u32)p;
        else      csr[base+pos] = (int)(u32)p;
    }
    __syncthreads();
    if (fits){
        for (int i=t; i<n; i+=256) csr[base+i] = vals[i];
    }
}

// ---------- XCD-sliced CSR-gather segment mean (slice-major table) ----------
// 4 lanes per dest row. Main loop: 8 incidences/iter, fully branch-free —
// 8 scalar csr loads (uniform within the 4-lane group -> TA broadcast, L1/L2-cached)
// then 8 unconditional 16-B gathers in flight. Tail (<8): loads from valid rows
// (repeat idx j0), contributions zeroed via cndmask (no branches, no 0*NaN).
// csr/table loads cached; all outputs non-temporal (consumed cross-XCD via L3).
// MODE 0: out bf16 slice-major | MODE 1: out bf16 row-major, + bias + prelu
// MODE 2: out fp32 row-major, + bias + resid + prelu
template<int MODE>
__global__ __launch_bounds__(256) void k_aggs(const u32* __restrict__ tab, const int* __restrict__ csr,
                                              const int* __restrict__ off, void* __restrict__ outp,
                                              const float* __restrict__ bias, const float* __restrict__ resid,
                                              const float* __restrict__ aptr, int nrows){
    int slice = blockIdx.x & 3;
    int dt    = blockIdx.x >> 2;
    int t = threadIdx.x;
    int lane = t & 63;
    int grp = lane >> 2, c4 = lane & 3;
    int d = dt*64 + ((t>>6)<<4) + grp;
    if (d >= nrows) return;
    int start = off[d], end = off[d+1];
    int deg = end - start;
    const u32* tslice = tab + (size_t)slice*nrows*16 + (c4<<2);   // slice-row stride: 16 u32

    float a0=0.f,a1=0.f,a2=0.f,a3=0.f,a4=0.f,a5=0.f,a6=0.f,a7=0.f;
    int pos = start;
    // ---- main: 8 gathers in flight, no branches, no masks ----
    for (; pos + 8 <= end; pos += 8){
        int j0 = csr[pos+0]; int j1 = csr[pos+1]; int j2 = csr[pos+2]; int j3 = csr[pos+3];
        int j4 = csr[pos+4]; int j5 = csr[pos+5]; int j6 = csr[pos+6]; int j7 = csr[pos+7];
        u32x4 v0 = *reinterpret_cast<const u32x4*>(tslice + (size_t)j0*16);
        u32x4 v1 = *reinterpret_cast<const u32x4*>(tslice + (size_t)j1*16);
        u32x4 v2 = *reinterpret_cast<const u32x4*>(tslice + (size_t)j2*16);
        u32x4 v3 = *reinterpret_cast<const u32x4*>(tslice + (size_t)j3*16);
        u32x4 v4 = *reinterpret_cast<const u32x4*>(tslice + (size_t)j4*16);
        u32x4 v5 = *reinterpret_cast<const u32x4*>(tslice + (size_t)j5*16);
        u32x4 v6 = *reinterpret_cast<const u32x4*>(tslice + (size_t)j6*16);
        u32x4 v7 = *reinterpret_cast<const u32x4*>(tslice + (size_t)j7*16);
        a0 += blo(v0.x)+blo(v1.x)+blo(v2.x)+blo(v3.x)+blo(v4.x)+blo(v5.x)+blo(v6.x)+blo(v7.x);
        a1 += bhi(v0.x)+bhi(v1.x)+bhi(v2.x)+bhi(v3.x)+bhi(v4.x)+bhi(v5.x)+bhi(v6.x)+bhi(v7.x);
        a2 += blo(v0.y)+blo(v1.y)+blo(v2.y)+blo(v3.y)+blo(v4.y)+blo(v5.y)+blo(v6.y)+blo(v7.y);
        a3 += bhi(v0.y)+bhi(v1.y)+bhi(v2.y)+bhi(v3.y)+bhi(v4.y)+bhi(v5.y)+bhi(v6.y)+bhi(v7.y);
        a4 += blo(v0.z)+blo(v1.z)+blo(v2.z)+blo(v3.z)+blo(v4.z)+blo(v5.z)+blo(v6.z)+blo(v7.z);
        a5 += bhi(v0.z)+bhi(v1.z)+bhi(v2.z)+bhi(v3.z)+bhi(v4.z)+bhi(v5.z)+bhi(v6.z)+bhi(v7.z);
        a6 += blo(v0.w)+blo(v1.w)+blo(v2.w)+blo(v3.w)+blo(v4.w)+blo(v5.w)+blo(v6.w)+blo(v7.w);
        a7 += bhi(v0.w)+bhi(v1.w)+bhi(v2.w)+bhi(v3.w)+bhi(v4.w)+bhi(v5.w)+bhi(v6.w)+bhi(v7.w);
    }
    // ---- tail: <8 remaining; clamped loads from valid rows, masked by cndmask ----
    for (; pos < end; pos += 4){
        int lim = end - pos;                 // >= 1
        int j0 = csr[pos];
        int j1 = (lim > 1) ? csr[pos+1] : j0;
        int j2 = (lim > 2) ? csr[pos+2] : j0;
        int j3 = (lim > 3) ? csr[pos+3] : j0;
        u32x4 z = (u32x4){0u,0u,0u,0u};
        u32x4 v0 = *reinterpret_cast<const u32x4*>(tslice + (size_t)j0*16);
        u32x4 v1 = *reinterpret_cast<const u32x4*>(tslice + (size_t)j1*16);
        u32x4 v2 = *reinterpret_cast<const u32x4*>(tslice + (size_t)j2*16);
        u32x4 v3 = *reinterpret_cast<const u32x4*>(tslice + (size_t)j3*16);
        v1 = (lim > 1) ? v1 : z;
        v2 = (lim > 2) ? v2 : z;
        v3 = (lim > 3) ? v3 : z;
        a0 += blo(v0.x)+blo(v1.x)+blo(v2.x)+blo(v3.x);
        a1 += bhi(v0.x)+bhi(v1.x)+bhi(v2.x)+bhi(v3.x);
        a2 += blo(v0.y)+blo(v1.y)+blo(v2.y)+blo(v3.y);
        a3 += bhi(v0.y)+bhi(v1.y)+bhi(v2.y)+bhi(v3.y);
        a4 += blo(v0.z)+blo(v1.z)+blo(v2.z)+blo(v3.z);
        a5 += bhi(v0.z)+bhi(v1.z)+bhi(v2.z)+bhi(v3.z);
        a6 += blo(v0.w)+blo(v1.w)+blo(v2.w)+blo(v3.w);
        a7 += bhi(v0.w)+bhi(v1.w)+bhi(v2.w)+bhi(v3.w);
    }
    float s = (deg > 0) ? 1.0f/(float)deg : 0.f;
    a0*=s; a1*=s; a2*=s; a3*=s; a4*=s; a5*=s; a6*=s; a7*=s;
    if constexpr (MODE >= 1){
        const f32x4* bp = reinterpret_cast<const f32x4*>(bias + slice*32 + (c4<<3));
        f32x4 b0 = bp[0], b1v = bp[1];
        a0+=b0.x; a1+=b0.y; a2+=b0.z; a3+=b0.w;
        a4+=b1v.x; a5+=b1v.y; a6+=b1v.z; a7+=b1v.w;
        if constexpr (MODE == 2){
            const f32x4* rp = reinterpret_cast<const f32x4*>(resid + (size_t)d*HID + slice*32 + (c4<<3));
            f32x4 r0 = rp[0], r1 = rp[1];
            a0+=r0.x; a1+=r0.y; a2+=r0.z; a3+=r0.w;
            a4+=r1.x; a5+=r1.y; a6+=r1.z; a7+=r1.w;
        }
        float al = aptr[0];
        a0 = (a0>=0.f)? a0 : al*a0;  a1 = (a1>=0.f)? a1 : al*a1;
        a2 = (a2>=0.f)? a2 : al*a2;  a3 = (a3>=0.f)? a3 : al*a3;
        a4 = (a4>=0.f)? a4 : al*a4;  a5 = (a5>=0.f)? a5 : al*a5;
        a6 = (a6>=0.f)? a6 : al*a6;  a7 = (a7>=0.f)? a7 : al*a7;
    }
    if constexpr (MODE == 2){
        f32x4* op = reinterpret_cast<f32x4*>((float*)outp + (size_t)d*HID + slice*32 + (c4<<3));
        __builtin_nontemporal_store((f32x4){a0,a1,a2,a3}, op);
        __builtin_nontemporal_store((f32x4){a4,a5,a6,a7}, op + 1);
    } else if constexpr (MODE == 1){
        // row-major bf16 (feeds the dense GEMM)
        u32x4 wv4 = (u32x4){ pk(a0,a1), pk(a2,a3), pk(a4,a5), pk(a6,a7) };
        __builtin_nontemporal_store(wv4,
            reinterpret_cast<u32x4*>((u32*)outp + (size_t)d*64 + slice*16 + (c4<<2)));
    } else {
        // slice-major bf16 (feeds the next sliced gather)
        u32x4 wv4 = (u32x4){ pk(a0,a1), pk(a2,a3), pk(a4,a5), pk(a6,a7) };
        __builtin_nontemporal_store(wv4,
            reinterpret_cast<u32x4*>((u32*)outp + ((size_t)slice*nrows + d)*16 + (c4<<2)));
    }
}

// ---------- standalone bf16 GEMM: C = A(bf16 row-major) @ Wf, slice-major output ----------
__global__ __launch_bounds__(256) void k_gemm_bf(const u16* __restrict__ A, const u16* __restrict__ Wf,
                                                 u16* __restrict__ C, int M){
    int wave = blockIdx.x*4 + ((int)threadIdx.x>>6);
    int lane = threadIdx.x & 63;
    int rtiles = M >> 4;
    if (wave >= rtiles) return;
    int row0 = wave << 4;
    const u16* Arow = A + (size_t)(row0 + (lane&15))*HID + ((lane>>4)<<3);
    const bf16x8* Wp = reinterpret_cast<const bf16x8*>(Wf) + lane;
    f32x4 acc[8];
    #pragma unroll
    for (int j=0;j<8;++j) acc[j] = (f32x4){0.f,0.f,0.f,0.f};
    #pragma unroll
    for (int s=0;s<4;++s){
        bf16x8 a = *reinterpret_cast<const bf16x8*>(Arow + s*32);
        #pragma unroll
        for (int j=0;j<8;++j){
            bf16x8 b = Wp[(s*8 + j)*64];
            acc[j] = __builtin_amdgcn_mfma_f32_16x16x32_bf16(a, b, acc[j], 0, 0, 0);
        }
    }
    int r0 = row0 + ((lane>>4)<<2);
    int c0 = lane & 15;
    #pragma unroll
    for (int j=0;j<8;++j){
        size_t sb = ((size_t)(j>>1)*M)*32 + ((j&1)<<4) + c0;
        #pragma unroll
        for (int r=0;r<4;++r){
            __builtin_nontemporal_store((u16)f2bfu(acc[j][r]), &C[sb + (size_t)(r0+r)*32]);
        }
    }
}

extern "C" void kernel_launch(void* const* d_in, const int* in_sizes, int n_in,
                              void* d_out, int out_size, void* d_ws, size_t ws_size,
                              hipStream_t stream){
    (void)n_in; (void)out_size; (void)ws_size;
    const float* x  = (const float*)d_in[0];
    const int*  hei = (const int*)  d_in[1];
    const float* W1 = (const float*)d_in[2];
    const float* b1 = (const float*)d_in[3];
    const float* W2 = (const float*)d_in[4];
    const float* b2 = (const float*)d_in[5];
    const float* ap = (const float*)d_in[6];

    const int nN = in_sizes[0] / HID;   // 50000
    const int nE = in_sizes[1] / 2;     // 600000
    const int* nidx = hei;
    const int* eidx = hei + nE;
    const int nkeys = 2*nN;
    const int nb    = (nkeys + KPB - 1) / KPB;   // 391

    char* w = (char*)d_ws;
    size_t o = 0;
    auto alloc = [&](size_t bytes)->void*{
        void* p = (void*)(w + o);
        o += (bytes + 255) & ~(size_t)255;
        return p;
    };
    int* hist  = (int*)alloc((size_t)NBMAX*sizeof(int));
    int* bfill = (int*)alloc((size_t)NBMAX*sizeof(int));
    int* off   = (int*)alloc(((size_t)nkeys+1)*sizeof(int));
    int* csr   = (int*)alloc((size_t)2*nE*sizeof(int));
    u64* pairs = (u64*)alloc((size_t)2*nE*sizeof(u64));
    u16* bufB  = (u16*)alloc((size_t)nN*HID*sizeof(u16));   // xw / hw (slice-major)
    u16* bufC  = (u16*)alloc((size_t)nN*HID*sizeof(u16));   // m / m2  (slice-major)
    u16* bufH  = (u16*)alloc((size_t)nN*HID*sizeof(u16));   // h (row-major, GEMM input)
    u16* w1f   = (u16*)alloc((size_t)HID*HID*sizeof(u16));
    u16* w2f   = (u16*)alloc((size_t)HID*HID*sizeof(u16));

    hipMemsetAsync(hist, 0, (size_t)2*NBMAX*sizeof(int), stream);   // hist + bfill (contiguous)

    const int pgrid  = (nE + IPB - 1)/IPB;       // 293
    const int rtiles = nN/16;                    // 3125
    const int ggrid  = (rtiles + 3)/4;           // 782
    const int dblk   = (nN + 63)/64;             // 782 dest tiles
    const int agrid  = 4*dblk;                   // × 4 column slices

    // K1: hist ∪ wfrag
    k_hist_wfrag<<<pgrid + 128, 256, 0, stream>>>(nidx, eidx, hist, nE, nN, nb, pgrid, W1, W2, w1f, w2f);
    // K2: part ∪ layer-1 gemm (fp32 A): xw = x @ W1 -> bufB (slice-major)
    k_part_gemm<<<pgrid + ggrid, 256, 0, stream>>>(nidx, eidx, hist, bfill, pairs, nE, nN, nb, pgrid,
                                                   x, w1f, bufB, nN);
    // K3: bucket (also writes off sentinel)
    k_bucket<<<nb, 256, 0, stream>>>(pairs, hist, csr, off, nkeys, nb, 2*nE);

    // layer 1: m = B^-1 H^T xw    (hyperedge side) -> bufC (slice-major)
    k_aggs<0><<<agrid, 256, 0, stream>>>((const u32*)bufB, csr, off + nN, bufC, nullptr, nullptr, nullptr, nN);
    // h = prelu(D^-1 H m + b1)    (node side) -> bufH (row-major)
    k_aggs<1><<<agrid, 256, 0, stream>>>((const u32*)bufC, csr, off, bufH, b1, nullptr, ap, nN);
    // hw = h @ W2 -> bufB (slice-major)
    k_gemm_bf<<<ggrid, 256, 0, stream>>>(bufH, w2f, bufB, nN);
    // layer 2: m2 = B^-1 H^T hw -> bufC (slice-major)
    k_aggs<0><<<agrid, 256, 0, stream>>>((const u32*)bufB, csr, off + nN, bufC, nullptr, nullptr, nullptr, nN);
    // out = prelu(D^-1 H m2 + b2 + x)
    k_aggs<2><<<agrid, 256, 0, stream>>>((const u32*)bufC, csr, off, d_out, b2, x, ap, nN);
}

// Round 5
// 228.707 us; speedup vs baseline: 2.6530x; 1.0071x over previous
//
#include <hip/hip_runtime.h>

typedef unsigned short u16;
typedef unsigned int   u32;
typedef unsigned long long u64;

#define HID 128
#define KPB 256      // keys per coarse bucket (shift 8)
#define NBMAX 512    // max coarse buckets (actual: 391)
#define IPB 2048     // incidences per partition workgroup
#define CAP 6144     // LDS val-staging capacity per bucket (mean ~3070)

typedef __bf16 bf16x8 __attribute__((ext_vector_type(8)));
typedef float  f32x4  __attribute__((ext_vector_type(4)));
typedef u32    u32x4  __attribute__((ext_vector_type(4)));

__device__ inline float u2f(u32 u){ union{u32 u;float f;} v; v.u=u; return v.f; }
__device__ inline u32   f2u(float f){ union{float f;u32 u;} v; v.f=f; return v.u; }
__device__ inline u32  f2bfu(float f){ u32 b=f2u(f); return ((b + 0x7FFFu + ((b>>16)&1u))>>16)&0xFFFFu; }
__device__ inline float blo(u32 u){ return u2f(u<<16); }
__device__ inline float bhi(u32 u){ return u2f(u & 0xFFFF0000u); }
__device__ inline u32  pk(float lo, float hi){ return (f2bfu(hi)<<16) | f2bfu(lo); }

// 2-slice table layout: tab[2][M][64] u16 — slice s is a contiguous 6.4 MB block,
// slice-rows are 128 B = exactly one cache line, fully consumed by the 8-lane group
// => 2 line-misses per incidence (was 4 half-used in r4, 2 at L3 latency in r0).
// slice = blockIdx&1; XCD k (= blockIdx%8) only touches slice k&1 (4 XCDs/slice,
// ~62% L2-resident). Outputs are non-temporal so they don't evict the table.

// ---------- K1: coarse histogram (blocks [0,nhb)) ∪ W-fragment conversion (rest) ----------
__global__ __launch_bounds__(256) void k_hist_wfrag(const int* __restrict__ nidx, const int* __restrict__ eidx,
                                                    int* __restrict__ hist, int nE, int nN, int nb, int nhb,
                                                    const float* __restrict__ W1, const float* __restrict__ W2,
                                                    u16* __restrict__ W1f, u16* __restrict__ W2f){
    __shared__ int h[NBMAX];
    if ((int)blockIdx.x < nhb){
        for (int t=threadIdx.x; t<nb; t+=256) h[t]=0;
        __syncthreads();
        int base = blockIdx.x*IPB;
        for (int k=threadIdx.x; k<IPB; k+=256){
            int j = base+k;
            if (j < nE){
                atomicAdd(&h[nidx[j]>>8], 1);
                atomicAdd(&h[(nN+eidx[j])>>8], 1);
            }
        }
        __syncthreads();
        for (int t=threadIdx.x; t<nb; t+=256) if (h[t]) atomicAdd(&hist[t], h[t]);
    } else {
        int gid = ((int)blockIdx.x - nhb)*256 + threadIdx.x;   // 32768 total
        const float* W = (gid < 16384) ? W1 : W2;
        u16* Wf = (gid < 16384) ? W1f : W2f;
        int id = gid & 16383;
        int i = id & 7, l = (id>>3)&63, j = (id>>9)&7, s = id>>12;
        Wf[id] = (u16)f2bfu(W[(s*32 + ((l>>4)<<3) + i)*HID + (j<<4) + (l&15)]);
    }
}

// ---------- K2: partition into buckets (blocks [0,npb)) ∪ layer-1 GEMM fp32-A (rest) ----------
// GEMM epilogue writes 2-SLICE-MAJOR: C[((j>>2)*M + row)*64 + (j&3)*16 + c0]
__global__ __launch_bounds__(256) void k_part_gemm(const int* __restrict__ nidx, const int* __restrict__ eidx,
                                                   const int* __restrict__ hist, int* __restrict__ bfill,
                                                   u64* __restrict__ pairs, int nE, int nN, int nb, int npb,
                                                   const float* __restrict__ A, const u16* __restrict__ Wf,
                                                   u16* __restrict__ C, int M){
    __shared__ int h[NBMAX], rsv[NBMAX], fl[NBMAX], bb[NBMAX], sd[256];
    int t = threadIdx.x;
    if ((int)blockIdx.x < npb){
        for (int i=t; i<nb; i+=256){ h[i]=0; fl[i]=0; }
        __syncthreads();
        int base = blockIdx.x*IPB;
        for (int k=t; k<IPB; k+=256){
            int j = base+k;
            if (j < nE){
                atomicAdd(&h[nidx[j]>>8], 1);
                atomicAdd(&h[(nN+eidx[j])>>8], 1);
            }
        }
        int c0 = (2*t   < nb) ? hist[2*t]   : 0;
        int c1 = (2*t+1 < nb) ? hist[2*t+1] : 0;
        int s = c0 + c1;
        sd[t] = s; __syncthreads();
        for (int o=1;o<256;o<<=1){ int u = (t>=o)? sd[t-o] : 0; __syncthreads(); sd[t]+=u; __syncthreads(); }
        int ex = sd[t] - s;
        if (2*t   < nb) bb[2*t]   = ex;
        if (2*t+1 < nb) bb[2*t+1] = ex + c0;
        __syncthreads();
        for (int i=t; i<nb; i+=256){ if (h[i]) rsv[i] = bb[i] + atomicAdd(&bfill[i], h[i]); }
        __syncthreads();
        for (int k=t; k<IPB; k+=256){
            int j = base+k;
            if (j < nE){
                int n = nidx[j], e = eidx[j];
                int b1 = n>>8;
                int p1 = rsv[b1] + atomicAdd(&fl[b1], 1);
                pairs[p1] = ((u64)(u32)n << 32) | (u32)e;
                int k2 = nN + e;
                int b2 = k2>>8;
                int p2 = rsv[b2] + atomicAdd(&fl[b2], 1);
                pairs[p2] = ((u64)(u32)k2 << 32) | (u32)n;
            }
        }
    } else {
        int wave = ((int)blockIdx.x - npb)*4 + (t>>6);
        int lane = t & 63;
        int rtiles = M >> 4;
        if (wave >= rtiles) return;
        int row0 = wave << 4;
        const float* Arow = A + (size_t)(row0 + (lane&15))*HID + ((lane>>4)<<3);
        const bf16x8* Wp = reinterpret_cast<const bf16x8*>(Wf) + lane;
        f32x4 acc[8];
        #pragma unroll
        for (int j=0;j<8;++j) acc[j] = (f32x4){0.f,0.f,0.f,0.f};
        #pragma unroll
        for (int s=0;s<4;++s){
            float4 f0 = *reinterpret_cast<const float4*>(Arow + s*32);
            float4 f1 = *reinterpret_cast<const float4*>(Arow + s*32 + 4);
            union { u16 h[8]; bf16x8 v; } au;
            au.h[0]=(u16)f2bfu(f0.x); au.h[1]=(u16)f2bfu(f0.y); au.h[2]=(u16)f2bfu(f0.z); au.h[3]=(u16)f2bfu(f0.w);
            au.h[4]=(u16)f2bfu(f1.x); au.h[5]=(u16)f2bfu(f1.y); au.h[6]=(u16)f2bfu(f1.z); au.h[7]=(u16)f2bfu(f1.w);
            #pragma unroll
            for (int j=0;j<8;++j){
                bf16x8 b = Wp[(s*8 + j)*64];
                acc[j] = __builtin_amdgcn_mfma_f32_16x16x32_bf16(au.v, b, acc[j], 0, 0, 0);
            }
        }
        int r0 = row0 + ((lane>>4)<<2);
        int c0 = lane & 15;
        #pragma unroll
        for (int j=0;j<8;++j){
            size_t sb = ((size_t)(j>>2)*M)*64 + ((j&3)<<4) + c0;
            #pragma unroll
            for (int r=0;r<4;++r){
                __builtin_nontemporal_store((u16)f2bfu(acc[j][r]), &C[sb + (size_t)(r0+r)*64]);
            }
        }
    }
}

// ---------- per-bucket fine counting sort in LDS (computes own base locally) ----------
__global__ __launch_bounds__(256) void k_bucket(const u64* __restrict__ pairs, const int* __restrict__ hist,
                                                int* __restrict__ csr, int* __restrict__ off,
                                                int nkeys, int nb, int total){
    __shared__ int cntS[KPB];
    __shared__ int fillS[KPB];
    __shared__ int bbS[NBMAX+1];
    __shared__ int sd[256];
    __shared__ int vals[CAP];
    int b = blockIdx.x;
    int t = threadIdx.x;
    if (b == 0 && t == 0) off[nkeys] = total;
    int c0 = (2*t   < nb) ? hist[2*t]   : 0;
    int c1 = (2*t+1 < nb) ? hist[2*t+1] : 0;
    int s = c0 + c1;
    sd[t] = s; __syncthreads();
    for (int o=1;o<256;o<<=1){ int u = (t>=o)? sd[t-o] : 0; __syncthreads(); sd[t]+=u; __syncthreads(); }
    int ex = sd[t] - s;
    if (2*t   <= nb) bbS[2*t]   = ex;
    if (2*t+1 <= nb) bbS[2*t+1] = ex + c0;
    __syncthreads();
    int base = bbS[b];
    int n = bbS[b+1] - base;
    int k0 = b * KPB;

    cntS[t] = 0;
    __syncthreads();
    for (int i=t; i<n; i+=256){
        u64 p = pairs[base+i];
        atomicAdd(&cntS[(int)(p>>32) - k0], 1);
    }
    __syncthreads();
    int c = cntS[t];
    __syncthreads();
    fillS[t] = c; __syncthreads();
    for (int o=1;o<256;o<<=1){ int u = (t>=o)? fillS[t-o] : 0; __syncthreads(); fillS[t]+=u; __syncthreads(); }
    int ex2 = fillS[t] - c;
    __syncthreads();
    fillS[t] = ex2;
    __syncthreads();
    int k = k0 + t;
    if (k < nkeys) off[k] = base + ex2;
    bool fits = (n <= CAP);
    for (int i=t; i<n; i+=256){
        u64 p = pairs[base+i];
        int kl = (int)(p>>32) - k0;
        int pos = atomicAdd(&fillS[kl], 1);
        if (fits) vals[pos] = (int)(u32)p;
        else      csr[base+pos] = (int)(u32)p;
    }
    __syncthreads();
    if (fits){
        for (int i=t; i<n; i+=256) csr[base+i] = vals[i];
    }
}

// ---------- XCD-sliced CSR-gather segment mean (2-slice table, 128 B slice-rows) ----------
// 8 lanes per dest row; slice-row = one full 128 B line, fully consumed by the group.
// Main loop: 8 incidences/iter, branch-free — 8 scalar csr loads (uniform within the
// 8-lane group -> TA broadcast, cached) then 8 unconditional 16-B gathers in flight.
// Tail (<8): clamped loads from valid rows, contributions zeroed via cndmask.
// csr/table loads cached; all outputs non-temporal (consumed cross-XCD via L3).
// MODE 0: out bf16 slice-major | MODE 1: out bf16 row-major, + bias + prelu
// MODE 2: out fp32 row-major, + bias + resid + prelu
template<int MODE>
__global__ __launch_bounds__(256) void k_aggs(const u32* __restrict__ tab, const int* __restrict__ csr,
                                              const int* __restrict__ off, void* __restrict__ outp,
                                              const float* __restrict__ bias, const float* __restrict__ resid,
                                              const float* __restrict__ aptr, int nrows){
    int slice = blockIdx.x & 1;
    int dt    = blockIdx.x >> 1;
    int t = threadIdx.x;
    int lane = t & 63;
    int grp = lane >> 3, c8 = lane & 7;
    int d = dt*32 + ((t>>6)<<3) + grp;
    if (d >= nrows) return;
    int start = off[d], end = off[d+1];
    int deg = end - start;
    const u32* tslice = tab + (size_t)slice*nrows*32 + (c8<<2);   // slice-row stride: 32 u32 (128 B)

    float a0=0.f,a1=0.f,a2=0.f,a3=0.f,a4=0.f,a5=0.f,a6=0.f,a7=0.f;
    int pos = start;
    // ---- main: 8 gathers in flight, no branches, no masks ----
    for (; pos + 8 <= end; pos += 8){
        int j0 = csr[pos+0]; int j1 = csr[pos+1]; int j2 = csr[pos+2]; int j3 = csr[pos+3];
        int j4 = csr[pos+4]; int j5 = csr[pos+5]; int j6 = csr[pos+6]; int j7 = csr[pos+7];
        u32x4 v0 = *reinterpret_cast<const u32x4*>(tslice + (size_t)j0*32);
        u32x4 v1 = *reinterpret_cast<const u32x4*>(tslice + (size_t)j1*32);
        u32x4 v2 = *reinterpret_cast<const u32x4*>(tslice + (size_t)j2*32);
        u32x4 v3 = *reinterpret_cast<const u32x4*>(tslice + (size_t)j3*32);
        u32x4 v4 = *reinterpret_cast<const u32x4*>(tslice + (size_t)j4*32);
        u32x4 v5 = *reinterpret_cast<const u32x4*>(tslice + (size_t)j5*32);
        u32x4 v6 = *reinterpret_cast<const u32x4*>(tslice + (size_t)j6*32);
        u32x4 v7 = *reinterpret_cast<const u32x4*>(tslice + (size_t)j7*32);
        a0 += blo(v0.x)+blo(v1.x)+blo(v2.x)+blo(v3.x)+blo(v4.x)+blo(v5.x)+blo(v6.x)+blo(v7.x);
        a1 += bhi(v0.x)+bhi(v1.x)+bhi(v2.x)+bhi(v3.x)+bhi(v4.x)+bhi(v5.x)+bhi(v6.x)+bhi(v7.x);
        a2 += blo(v0.y)+blo(v1.y)+blo(v2.y)+blo(v3.y)+blo(v4.y)+blo(v5.y)+blo(v6.y)+blo(v7.y);
        a3 += bhi(v0.y)+bhi(v1.y)+bhi(v2.y)+bhi(v3.y)+bhi(v4.y)+bhi(v5.y)+bhi(v6.y)+bhi(v7.y);
        a4 += blo(v0.z)+blo(v1.z)+blo(v2.z)+blo(v3.z)+blo(v4.z)+blo(v5.z)+blo(v6.z)+blo(v7.z);
        a5 += bhi(v0.z)+bhi(v1.z)+bhi(v2.z)+bhi(v3.z)+bhi(v4.z)+bhi(v5.z)+bhi(v6.z)+bhi(v7.z);
        a6 += blo(v0.w)+blo(v1.w)+blo(v2.w)+blo(v3.w)+blo(v4.w)+blo(v5.w)+blo(v6.w)+blo(v7.w);
        a7 += bhi(v0.w)+bhi(v1.w)+bhi(v2.w)+bhi(v3.w)+bhi(v4.w)+bhi(v5.w)+bhi(v6.w)+bhi(v7.w);
    }
    // ---- tail: <8 remaining; clamped loads from valid rows, masked by cndmask ----
    for (; pos < end; pos += 4){
        int lim = end - pos;                 // >= 1
        int j0 = csr[pos];
        int j1 = (lim > 1) ? csr[pos+1] : j0;
        int j2 = (lim > 2) ? csr[pos+2] : j0;
        int j3 = (lim > 3) ? csr[pos+3] : j0;
        u32x4 z = (u32x4){0u,0u,0u,0u};
        u32x4 v0 = *reinterpret_cast<const u32x4*>(tslice + (size_t)j0*32);
        u32x4 v1 = *reinterpret_cast<const u32x4*>(tslice + (size_t)j1*32);
        u32x4 v2 = *reinterpret_cast<const u32x4*>(tslice + (size_t)j2*32);
        u32x4 v3 = *reinterpret_cast<const u32x4*>(tslice + (size_t)j3*32);
        v1 = (lim > 1) ? v1 : z;
        v2 = (lim > 2) ? v2 : z;
        v3 = (lim > 3) ? v3 : z;
        a0 += blo(v0.x)+blo(v1.x)+blo(v2.x)+blo(v3.x);
        a1 += bhi(v0.x)+bhi(v1.x)+bhi(v2.x)+bhi(v3.x);
        a2 += blo(v0.y)+blo(v1.y)+blo(v2.y)+blo(v3.y);
        a3 += bhi(v0.y)+bhi(v1.y)+bhi(v2.y)+bhi(v3.y);
        a4 += blo(v0.z)+blo(v1.z)+blo(v2.z)+blo(v3.z);
        a5 += bhi(v0.z)+bhi(v1.z)+bhi(v2.z)+bhi(v3.z);
        a6 += blo(v0.w)+blo(v1.w)+blo(v2.w)+blo(v3.w);
        a7 += bhi(v0.w)+bhi(v1.w)+bhi(v2.w)+bhi(v3.w);
    }
    float s = (deg > 0) ? 1.0f/(float)deg : 0.f;
    a0*=s; a1*=s; a2*=s; a3*=s; a4*=s; a5*=s; a6*=s; a7*=s;
    if constexpr (MODE >= 1){
        const f32x4* bp = reinterpret_cast<const f32x4*>(bias + slice*64 + (c8<<3));
        f32x4 b0 = bp[0], b1v = bp[1];
        a0+=b0.x; a1+=b0.y; a2+=b0.z; a3+=b0.w;
        a4+=b1v.x; a5+=b1v.y; a6+=b1v.z; a7+=b1v.w;
        if constexpr (MODE == 2){
            const f32x4* rp = reinterpret_cast<const f32x4*>(resid + (size_t)d*HID + slice*64 + (c8<<3));
            f32x4 r0 = rp[0], r1 = rp[1];
            a0+=r0.x; a1+=r0.y; a2+=r0.z; a3+=r0.w;
            a4+=r1.x; a5+=r1.y; a6+=r1.z; a7+=r1.w;
        }
        float al = aptr[0];
        a0 = (a0>=0.f)? a0 : al*a0;  a1 = (a1>=0.f)? a1 : al*a1;
        a2 = (a2>=0.f)? a2 : al*a2;  a3 = (a3>=0.f)? a3 : al*a3;
        a4 = (a4>=0.f)? a4 : al*a4;  a5 = (a5>=0.f)? a5 : al*a5;
        a6 = (a6>=0.f)? a6 : al*a6;  a7 = (a7>=0.f)? a7 : al*a7;
    }
    if constexpr (MODE == 2){
        f32x4* op = reinterpret_cast<f32x4*>((float*)outp + (size_t)d*HID + slice*64 + (c8<<3));
        __builtin_nontemporal_store((f32x4){a0,a1,a2,a3}, op);
        __builtin_nontemporal_store((f32x4){a4,a5,a6,a7}, op + 1);
    } else if constexpr (MODE == 1){
        // row-major bf16 (feeds the dense GEMM)
        u32x4 wv4 = (u32x4){ pk(a0,a1), pk(a2,a3), pk(a4,a5), pk(a6,a7) };
        __builtin_nontemporal_store(wv4,
            reinterpret_cast<u32x4*>((u32*)outp + (size_t)d*64 + slice*32 + (c8<<2)));
    } else {
        // slice-major bf16 (feeds the next sliced gather)
        u32x4 wv4 = (u32x4){ pk(a0,a1), pk(a2,a3), pk(a4,a5), pk(a6,a7) };
        __builtin_nontemporal_store(wv4,
            reinterpret_cast<u32x4*>((u32*)outp + ((size_t)slice*nrows + d)*32 + (c8<<2)));
    }
}

// ---------- standalone bf16 GEMM: C = A(bf16 row-major) @ Wf, 2-slice-major output ----------
__global__ __launch_bounds__(256) void k_gemm_bf(const u16* __restrict__ A, const u16* __restrict__ Wf,
                                                 u16* __restrict__ C, int M){
    int wave = blockIdx.x*4 + ((int)threadIdx.x>>6);
    int lane = threadIdx.x & 63;
    int rtiles = M >> 4;
    if (wave >= rtiles) return;
    int row0 = wave << 4;
    const u16* Arow = A + (size_t)(row0 + (lane&15))*HID + ((lane>>4)<<3);
    const bf16x8* Wp = reinterpret_cast<const bf16x8*>(Wf) + lane;
    f32x4 acc[8];
    #pragma unroll
    for (int j=0;j<8;++j) acc[j] = (f32x4){0.f,0.f,0.f,0.f};
    #pragma unroll
    for (int s=0;s<4;++s){
        bf16x8 a = *reinterpret_cast<const bf16x8*>(Arow + s*32);
        #pragma unroll
        for (int j=0;j<8;++j){
            bf16x8 b = Wp[(s*8 + j)*64];
            acc[j] = __builtin_amdgcn_mfma_f32_16x16x32_bf16(a, b, acc[j], 0, 0, 0);
        }
    }
    int r0 = row0 + ((lane>>4)<<2);
    int c0 = lane & 15;
    #pragma unroll
    for (int j=0;j<8;++j){
        size_t sb = ((size_t)(j>>2)*M)*64 + ((j&3)<<4) + c0;
        #pragma unroll
        for (int r=0;r<4;++r){
            __builtin_nontemporal_store((u16)f2bfu(acc[j][r]), &C[sb + (size_t)(r0+r)*64]);
        }
    }
}

extern "C" void kernel_launch(void* const* d_in, const int* in_sizes, int n_in,
                              void* d_out, int out_size, void* d_ws, size_t ws_size,
                              hipStream_t stream){
    (void)n_in; (void)out_size; (void)ws_size;
    const float* x  = (const float*)d_in[0];
    const int*  hei = (const int*)  d_in[1];
    const float* W1 = (const float*)d_in[2];
    const float* b1 = (const float*)d_in[3];
    const float* W2 = (const float*)d_in[4];
    const float* b2 = (const float*)d_in[5];
    const float* ap = (const float*)d_in[6];

    const int nN = in_sizes[0] / HID;   // 50000
    const int nE = in_sizes[1] / 2;     // 600000
    const int* nidx = hei;
    const int* eidx = hei + nE;
    const int nkeys = 2*nN;
    const int nb    = (nkeys + KPB - 1) / KPB;   // 391

    char* w = (char*)d_ws;
    size_t o = 0;
    auto alloc = [&](size_t bytes)->void*{
        void* p = (void*)(w + o);
        o += (bytes + 255) & ~(size_t)255;
        return p;
    };
    int* hist  = (int*)alloc((size_t)NBMAX*sizeof(int));
    int* bfill = (int*)alloc((size_t)NBMAX*sizeof(int));
    int* off   = (int*)alloc(((size_t)nkeys+1)*sizeof(int));
    int* csr   = (int*)alloc((size_t)2*nE*sizeof(int));
    u64* pairs = (u64*)alloc((size_t)2*nE*sizeof(u64));
    u16* bufB  = (u16*)alloc((size_t)nN*HID*sizeof(u16));   // xw / hw (2-slice-major)
    u16* bufC  = (u16*)alloc((size_t)nN*HID*sizeof(u16));   // m / m2  (2-slice-major)
    u16* bufH  = (u16*)alloc((size_t)nN*HID*sizeof(u16));   // h (row-major, GEMM input)
    u16* w1f   = (u16*)alloc((size_t)HID*HID*sizeof(u16));
    u16* w2f   = (u16*)alloc((size_t)HID*HID*sizeof(u16));

    hipMemsetAsync(hist, 0, (size_t)2*NBMAX*sizeof(int), stream);   // hist + bfill (contiguous)

    const int pgrid  = (nE + IPB - 1)/IPB;       // 293
    const int rtiles = nN/16;                    // 3125
    const int ggrid  = (rtiles + 3)/4;           // 782
    const int dblk   = (nN + 31)/32;             // 1563 dest tiles (32 rows each)
    const int agrid  = 2*dblk;                   // × 2 column slices

    // K1: hist ∪ wfrag
    k_hist_wfrag<<<pgrid + 128, 256, 0, stream>>>(nidx, eidx, hist, nE, nN, nb, pgrid, W1, W2, w1f, w2f);
    // K2: part ∪ layer-1 gemm (fp32 A): xw = x @ W1 -> bufB (2-slice-major)
    k_part_gemm<<<pgrid + ggrid, 256, 0, stream>>>(nidx, eidx, hist, bfill, pairs, nE, nN, nb, pgrid,
                                                   x, w1f, bufB, nN);
    // K3: bucket (also writes off sentinel)
    k_bucket<<<nb, 256, 0, stream>>>(pairs, hist, csr, off, nkeys, nb, 2*nE);

    // layer 1: m = B^-1 H^T xw    (hyperedge side) -> bufC (2-slice-major)
    k_aggs<0><<<agrid, 256, 0, stream>>>((const u32*)bufB, csr, off + nN, bufC, nullptr, nullptr, nullptr, nN);
    // h = prelu(D^-1 H m + b1)    (node side) -> bufH (row-major)
    k_aggs<1><<<agrid, 256, 0, stream>>>((const u32*)bufC, csr, off, bufH, b1, nullptr, ap, nN);
    // hw = h @ W2 -> bufB (2-slice-major)
    k_gemm_bf<<<ggrid, 256, 0, stream>>>(bufH, w2f, bufB, nN);
    // layer 2: m2 = B^-1 H^T hw -> bufC (2-slice-major)
    k_aggs<0><<<agrid, 256, 0, stream>>>((const u32*)bufB, csr, off + nN, bufC, nullptr, nullptr, nullptr, nN);
    // out = prelu(D^-1 H m2 + b2 + x)
    k_aggs<2><<<agrid, 256, 0, stream>>>((const u32*)bufC, csr, off, d_out, b2, x, ap, nN);
}